// Round 2
// baseline (661.828 us; speedup 1.0000x reference)
//
#include <hip/hip_runtime.h>
#include <hip/hip_bf16.h>

typedef __attribute__((ext_vector_type(8))) short short8;
typedef __attribute__((ext_vector_type(4))) short short4v;
typedef __attribute__((ext_vector_type(4))) float f32x4;
typedef __attribute__((ext_vector_type(4))) int   int4v;
typedef __attribute__((ext_vector_type(2))) int   int2v;

#define NFEAT 64
#define IN_DIM 192
#define HID 128
#define OUTD 64
#define TILE 64
#define NBLK 256
#define XSTR 72     // shorts per X panel row (64 + 8 pad; 144B, 16B-aligned, dw%32=4 -> 2-way)
#define W1STR 200   // shorts per W1 row (192 + 8 pad; 400B, 16B-aligned, dw%32=4 -> 2-way)
#define W2STR 132   // shorts per W2 row (128 + 4 pad; 264B, 8B-aligned,  dw%32=2 -> 2-way)

#define X_SH  (2*3*64*XSTR)   // 27648 shorts (double-buffered 3 panels of [64][72])
#define W1_SH (HID*W1STR)     // 25600
#define W2_SH (OUTD*W2STR)    // 8448
#define SMEM_BYTES ((X_SH + W1_SH + W2_SH) * 2)   // 123392 B

__device__ __forceinline__ short f2bf(float f) {
  __hip_bfloat16 b = __float2bfloat16(f);   // RNE; compiler fuses pairs to v_cvt_pk_bf16_f32
  short s; __builtin_memcpy(&s, &b, 2); return s;
}

// shifted softplus: log(1+e^z) - ln2, computed in log2 domain (1 exp + 1 log)
__device__ __forceinline__ float sp_m_ln2(float z) {
  float t = __builtin_exp2f(z * 1.4426950408889634f);
  return 0.6931471805599453f * __builtin_log2f(1.0f + t) - 0.6931471805599453f;
}

// edges may arrive as int64 (jax x64 on) or int32 (x64 off). Detect: int64 => hi-words
// (odd int32 positions) of nonneg indices < 2^31 are all zero.
__global__ void detect_mode(const int* __restrict__ edges_i, int* __restrict__ flag) {
  __shared__ int cnt;
  if (threadIdx.x == 0) cnt = 0;
  __syncthreads();
  if (edges_i[2 * threadIdx.x + 1] == 0) atomicAdd(&cnt, 1);
  __syncthreads();
  if (threadIdx.x == 0) flag[0] = (cnt >= 250) ? 1 : 0;
}

__global__ __launch_bounds__(256, 1) void edge_mlp(
    const float* __restrict__ edge_state,
    const int*   __restrict__ edges_i,
    const float* __restrict__ node_state,
    const float* __restrict__ W1g, const float* __restrict__ b1g,
    const float* __restrict__ W2g, const float* __restrict__ b2g,
    float* __restrict__ out, const int* __restrict__ flag, int tiles)
{
  extern __shared__ char smem[];
  unsigned short* Xl  = (unsigned short*)smem;
  unsigned short* W1l = Xl + X_SH;
  unsigned short* W2l = W1l + W1_SH;

  const int tid = threadIdx.x;
  const int bid = blockIdx.x;
  if (bid >= tiles) return;                 // whole block exits together
  const int w   = tid >> 6;                 // wave 0..3, owns 16 edges of the 64-edge tile
  const int lg  = (tid >> 4) & 3;           // lane-group within wave
  const int li  = tid & 15;                 // lane within group
  const int srow = tid >> 2;                // staging: row 0..63
  const int sc   = tid & 3;                 // staging: 16-float quarter

  const bool idx64 = (flag[0] != 0);

  // ---- stage weights to LDS (bf16) ----
  #pragma unroll 1
  for (int g = tid; g < (HID*IN_DIM/4); g += NBLK) {         // 6144 float4
    int row = g / 48, c4 = g - row*48;
    f32x4 v = *(const f32x4*)(W1g + row*IN_DIM + c4*4);
    short4v s = { f2bf(v[0]), f2bf(v[1]), f2bf(v[2]), f2bf(v[3]) };
    *(short4v*)(W1l + row*W1STR + c4*4) = s;
  }
  #pragma unroll 1
  for (int g = tid; g < (OUTD*HID/4); g += NBLK) {           // 2048 float4
    int row = g / 32, c4 = g - row*32;
    f32x4 v = *(const f32x4*)(W2g + row*HID + c4*4);
    short4v s = { f2bf(v[0]), f2bf(v[1]), f2bf(v[2]), f2bf(v[3]) };
    *(short4v*)(W2l + row*W2STR + c4*4) = s;
  }

  // ---- bias fragments in registers ----
  f32x4 b1v[8];
  #pragma unroll
  for (int hi = 0; hi < 8; ++hi) b1v[hi] = *(const f32x4*)(b1g + hi*16 + 4*lg);
  float b2v[4];
  #pragma unroll
  for (int ni = 0; ni < 4; ++ni) b2v[ni] = b2g[ni*16 + li];

  // ---- first tile: indices + gather loads into regs ----
  int e0c, e1c;
  { int eb = bid*TILE;
    if (idx64) { int4v v = *(const int4v*)(edges_i + (long)(eb + srow)*4); e0c = v[0]; e1c = v[2]; }
    else       { int2v v = *(const int2v*)(edges_i + (long)(eb + srow)*2); e0c = v[0]; e1c = v[1]; }
  }
  f32x4 rn0[4], rn1[4], red[4];
  { const float* p0 = node_state + (long)e0c*NFEAT + sc*16;
    const float* p1 = node_state + (long)e1c*NFEAT + sc*16;
    const float* pe = edge_state + ((long)bid*TILE + srow)*NFEAT + sc*16;
    #pragma unroll
    for (int i = 0; i < 4; ++i) {
      rn0[i] = *(const f32x4*)(p0 + 4*i);
      rn1[i] = *(const f32x4*)(p1 + 4*i);
      red[i] = *(const f32x4*)(pe + 4*i);
    }
  }
  // prefetch indices for tile bid+NBLK
  int e0n = 0, e1n = 0;
  if (bid + NBLK < tiles) {
    int eb = (bid + NBLK)*TILE;
    if (idx64) { int4v v = *(const int4v*)(edges_i + (long)(eb + srow)*4); e0n = v[0]; e1n = v[2]; }
    else       { int2v v = *(const int2v*)(edges_i + (long)(eb + srow)*2); e0n = v[0]; e1n = v[1]; }
  }

  auto writeX = [&](int buf, const f32x4* rA, int panel) {
    unsigned short* dst = Xl + (((buf*3 + panel)*64) + srow)*XSTR + sc*16;
    short8 p0 = { f2bf(rA[0][0]), f2bf(rA[0][1]), f2bf(rA[0][2]), f2bf(rA[0][3]),
                  f2bf(rA[1][0]), f2bf(rA[1][1]), f2bf(rA[1][2]), f2bf(rA[1][3]) };
    short8 p1 = { f2bf(rA[2][0]), f2bf(rA[2][1]), f2bf(rA[2][2]), f2bf(rA[2][3]),
                  f2bf(rA[3][0]), f2bf(rA[3][1]), f2bf(rA[3][2]), f2bf(rA[3][3]) };
    *(short8*)(dst)     = p0;
    *(short8*)(dst + 8) = p1;
  };

  writeX(0, rn0, 0); writeX(0, rn1, 1); writeX(0, red, 2);
  __syncthreads();

  // ---- cache all W2 fragments in registers (shared k-permutation with GEMM2 A) ----
  short8 w2f[4][4];
  #pragma unroll
  for (int q = 0; q < 4; ++q)
    #pragma unroll
    for (int ni = 0; ni < 4; ++ni) {
      const unsigned short* base = W2l + (ni*16 + li)*W2STR + 32*q + 4*lg;
      short4v a = *(const short4v*)(base);
      short4v c = *(const short4v*)(base + 16);
      short8 t = { a[0], a[1], a[2], a[3], c[0], c[1], c[2], c[3] };
      w2f[q][ni] = t;
    }

  // ---- main loop over this block's tiles ----
  int k = 0;
  for (int t = bid; t < tiles; t += NBLK, ++k) {
    const int cur = k & 1;
    const bool hn = (t + NBLK) < tiles;

    // 1. issue gather loads for tile t+NBLK (hide HBM latency under compute)
    if (hn) {
      const float* p0 = node_state + (long)e0n*NFEAT + sc*16;
      const float* p1 = node_state + (long)e1n*NFEAT + sc*16;
      const float* pe = edge_state + ((long)(t + NBLK)*TILE + srow)*NFEAT + sc*16;
      #pragma unroll
      for (int i = 0; i < 4; ++i) {
        rn0[i] = *(const f32x4*)(p0 + 4*i);
        rn1[i] = *(const f32x4*)(p1 + 4*i);
        red[i] = *(const f32x4*)(pe + 4*i);
      }
    }
    // 2. prefetch indices two tiles ahead
    int e0p = 0, e1p = 0;
    if (t + 2*NBLK < tiles) {
      int eb = (t + 2*NBLK)*TILE;
      if (idx64) { int4v v = *(const int4v*)(edges_i + (long)(eb + srow)*4); e0p = v[0]; e1p = v[2]; }
      else       { int2v v = *(const int2v*)(edges_i + (long)(eb + srow)*2); e0p = v[0]; e1p = v[1]; }
    }

    // 3a. GEMM1 (swapped): D'[hidden][edge] = W1 . X^T, bias-initialized
    f32x4 acc1[8];
    #pragma unroll
    for (int hi = 0; hi < 8; ++hi) acc1[hi] = b1v[hi];
    #pragma unroll
    for (int ks = 0; ks < 6; ++ks) {
      const int p   = ks >> 1;
      const int ksh = (ks & 1)*32 + 8*lg;
      short8 bx = *(const short8*)(Xl + (((cur*3 + p)*64) + 16*w + li)*XSTR + ksh);
      #pragma unroll
      for (int hi = 0; hi < 8; ++hi) {
        short8 aw = *(const short8*)(W1l + (hi*16 + li)*W1STR + 32*ks + 8*lg);
        acc1[hi] = __builtin_amdgcn_mfma_f32_16x16x32_bf16(aw, bx, acc1[hi], 0, 0, 0);
      }
    }

    // 3b. shifted softplus + pack straight into GEMM2 A fragments (no LDS round-trip)
    short8 a2[4];
    #pragma unroll
    for (int q = 0; q < 4; ++q) {
      f32x4 lo = acc1[2*q], hi4 = acc1[2*q + 1];
      short8 v = { f2bf(sp_m_ln2(lo[0])),  f2bf(sp_m_ln2(lo[1])),
                   f2bf(sp_m_ln2(lo[2])),  f2bf(sp_m_ln2(lo[3])),
                   f2bf(sp_m_ln2(hi4[0])), f2bf(sp_m_ln2(hi4[1])),
                   f2bf(sp_m_ln2(hi4[2])), f2bf(sp_m_ln2(hi4[3])) };
      a2[q] = v;
    }

    // 3c. GEMM2: out[edge][feat] = H . W2^T, bias-initialized
    f32x4 acc2[4];
    #pragma unroll
    for (int ni = 0; ni < 4; ++ni) { f32x4 z = {b2v[ni], b2v[ni], b2v[ni], b2v[ni]}; acc2[ni] = z; }
    #pragma unroll
    for (int q = 0; q < 4; ++q)
      #pragma unroll
      for (int ni = 0; ni < 4; ++ni)
        acc2[ni] = __builtin_amdgcn_mfma_f32_16x16x32_bf16(a2[q], w2f[q][ni], acc2[ni], 0, 0, 0);

    // 3d. store (lanes 0-15 cover 64B contiguous per instr)
    { float* op = out + ((long)t*TILE + 16*w + 4*lg)*OUTD + li;
      #pragma unroll
      for (int ni = 0; ni < 4; ++ni)
        #pragma unroll
        for (int r = 0; r < 4; ++r)
          op[(long)r*OUTD + ni*16] = acc2[ni][r];
    }

    // 4. convert + write next tile into the other buffer
    if (hn) {
      writeX(cur ^ 1, rn0, 0); writeX(cur ^ 1, rn1, 1); writeX(cur ^ 1, red, 2);
    }
    __syncthreads();
    e0n = e0p; e1n = e1p;
  }
}

extern "C" void kernel_launch(void* const* d_in, const int* in_sizes, int n_in,
                              void* d_out, int out_size, void* d_ws, size_t ws_size,
                              hipStream_t stream) {
  const float* edge_state = (const float*)d_in[0];
  const int*   edges_i    = (const int*)d_in[1];
  const float* node_state = (const float*)d_in[2];
  const float* W1g        = (const float*)d_in[3];
  const float* b1g        = (const float*)d_in[4];
  const float* W2g        = (const float*)d_in[5];
  const float* b2g        = (const float*)d_in[6];
  float* out = (float*)d_out;
  int*   flag = (int*)d_ws;

  const int E = in_sizes[0] / NFEAT;      // 1,000,000
  const int tiles = E / TILE;             // 15,625 (exact)

  detect_mode<<<dim3(1), dim3(256), 0, stream>>>(edges_i, flag);

  (void)hipFuncSetAttribute((const void*)edge_mlp,
                            hipFuncAttributeMaxDynamicSharedMemorySize, SMEM_BYTES);
  edge_mlp<<<dim3(NBLK), dim3(256), SMEM_BYTES, stream>>>(
      edge_state, edges_i, node_state, W1g, b1g, W2g, b2g, out, flag, tiles);
}

// Round 3
// 492.988 us; speedup vs baseline: 1.3425x; 1.3425x over previous
//
#include <hip/hip_runtime.h>
#include <hip/hip_bf16.h>

typedef __attribute__((ext_vector_type(8))) short short8;
typedef __attribute__((ext_vector_type(4))) short short4v;
typedef __attribute__((ext_vector_type(4))) float f32x4;
typedef __attribute__((ext_vector_type(4))) int   int4v;
typedef __attribute__((ext_vector_type(2))) int   int2v;

#define NFEAT 64
#define IN_DIM 192
#define HID 128
#define OUTD 64
#define WTILE 16            // edges per wave-tile (one MFMA edge-group)
#define GRID 512
#define NWAVES (GRID*4)     // 2048 independent wave streams
#define XSTR 72             // shorts per X row (64 + 8 pad -> conflict-free b128)
#define W1STR 200           // shorts per W1 row (192 + 8 pad)
#define W2STR 132           // shorts per W2 row (staging only)

#define XPW   (3*WTILE*XSTR)          // 3456 shorts per wave (3 panels [16][72])
#define X_SH  (4*XPW)                 // 13824 shorts = 27648 B
#define W1_SH (HID*W1STR)             // 25600 shorts = 51200 B
#define SMEM_BYTES ((X_SH + W1_SH)*2) // 78848 B -> 2 blocks/CU (8 waves/CU)

__device__ __forceinline__ short f2bf(float f) {
  __hip_bfloat16 b = __float2bfloat16(f);
  short s; __builtin_memcpy(&s, &b, 2); return s;
}

// shifted softplus: log(1+e^z) - ln2 in log2 domain
__device__ __forceinline__ float sp_m_ln2(float z) {
  float t = __builtin_exp2f(z * 1.4426950408889634f);
  return 0.6931471805599453f * __builtin_log2f(1.0f + t) - 0.6931471805599453f;
}

// edges arrive as int64 (x64 on) or int32. int64 => odd int32 words all zero.
__global__ void detect_mode(const int* __restrict__ edges_i, int* __restrict__ flag) {
  __shared__ int cnt;
  if (threadIdx.x == 0) cnt = 0;
  __syncthreads();
  if (edges_i[2 * threadIdx.x + 1] == 0) atomicAdd(&cnt, 1);
  __syncthreads();
  if (threadIdx.x == 0) flag[0] = (cnt >= 250) ? 1 : 0;
}

__global__ __launch_bounds__(256, 2) void edge_mlp(
    const float* __restrict__ edge_state,
    const int*   __restrict__ edges_i,
    const float* __restrict__ node_state,
    const float* __restrict__ W1g, const float* __restrict__ b1g,
    const float* __restrict__ W2g, const float* __restrict__ b2g,
    float* __restrict__ out, const int* __restrict__ flag, int tiles16)
{
  extern __shared__ char smem[];
  unsigned short* Xl  = (unsigned short*)smem;
  unsigned short* W1l = Xl + X_SH;

  const int tid  = threadIdx.x;
  const int bid  = blockIdx.x;
  const int w    = tid >> 6;          // wave 0..3 (private X panels, no loop barriers)
  const int lane = tid & 63;
  const int lg   = (lane >> 4) & 3;   // lane-group
  const int li   = lane & 15;         // lane within group
  const int er   = lane >> 2;         // staging: edge-in-tile 0..15
  const int sc   = lane & 3;          // staging: 16-float quarter

  const bool idx64 = (flag[0] != 0);
  unsigned short* Xw = Xl + w * XPW;

  // ---- stage W1 to LDS (bf16); W2 staged temporarily into the X area ----
  #pragma unroll 1
  for (int g = tid; g < (HID*IN_DIM/4); g += 256) {
    int row = g / 48, c4 = g - row*48;
    f32x4 v = *(const f32x4*)(W1g + row*IN_DIM + c4*4);
    short4v s = { f2bf(v[0]), f2bf(v[1]), f2bf(v[2]), f2bf(v[3]) };
    *(short4v*)(W1l + row*W1STR + c4*4) = s;
  }
  #pragma unroll 1
  for (int g = tid; g < (OUTD*HID/4); g += 256) {
    int row = g / 32, c4 = g - row*32;
    f32x4 v = *(const f32x4*)(W2g + row*HID + c4*4);
    short4v s = { f2bf(v[0]), f2bf(v[1]), f2bf(v[2]), f2bf(v[3]) };
    *(short4v*)(Xl + row*W2STR + c4*4) = s;     // temp staging
  }
  __syncthreads();

  // ---- W2 fragments to registers (same k-permutation as GEMM2 A) ----
  short8 w2f[4][4];
  #pragma unroll
  for (int q = 0; q < 4; ++q)
    #pragma unroll
    for (int ni = 0; ni < 4; ++ni) {
      const unsigned short* base = Xl + (ni*16 + li)*W2STR + 32*q + 4*lg;
      short4v a = *(const short4v*)(base);
      short4v c = *(const short4v*)(base + 16);
      short8 t = { a[0], a[1], a[2], a[3], c[0], c[1], c[2], c[3] };
      w2f[q][ni] = t;
    }
  // bias fragments
  f32x4 b1v[8];
  #pragma unroll
  for (int hi = 0; hi < 8; ++hi) b1v[hi] = *(const f32x4*)(b1g + hi*16 + 4*lg);
  float b2v[4];
  #pragma unroll
  for (int ni = 0; ni < 4; ++ni) b2v[ni] = b2g[ni*16 + li];
  __syncthreads();     // everyone done reading W2 temp before X panels are written

  const int gw = bid*4 + w;            // global wave id, 0..2047

  auto loadIdx = [&](long t, int& a, int& b) {
    long e = (long)t*WTILE + er;
    if (idx64) { int4v v = *(const int4v*)(edges_i + e*4); a = v[0]; b = v[2]; }
    else       { int2v v = *(const int2v*)(edges_i + e*2); a = v[0]; b = v[1]; }
  };
  auto writeX = [&](const f32x4* rA, int panel) {
    unsigned short* dst = Xw + (panel*WTILE + er)*XSTR + sc*16;
    short8 p0 = { f2bf(rA[0][0]), f2bf(rA[0][1]), f2bf(rA[0][2]), f2bf(rA[0][3]),
                  f2bf(rA[1][0]), f2bf(rA[1][1]), f2bf(rA[1][2]), f2bf(rA[1][3]) };
    short8 p1 = { f2bf(rA[2][0]), f2bf(rA[2][1]), f2bf(rA[2][2]), f2bf(rA[2][3]),
                  f2bf(rA[3][0]), f2bf(rA[3][1]), f2bf(rA[3][2]), f2bf(rA[3][3]) };
    *(short8*)(dst)     = p0;
    *(short8*)(dst + 8) = p1;
  };

  // ---- prologue: tile gw into regs, then LDS ----
  int e0c, e1c, e0n = 0, e1n = 0;
  f32x4 rn0[4], rn1[4], red[4];
  if (gw < tiles16) {
    loadIdx(gw, e0c, e1c);
    const float* p0 = node_state + (long)e0c*NFEAT + sc*16;
    const float* p1 = node_state + (long)e1c*NFEAT + sc*16;
    const float* pe = edge_state + ((long)gw*WTILE + er)*NFEAT + sc*16;
    #pragma unroll
    for (int i = 0; i < 4; ++i) {
      rn0[i] = *(const f32x4*)(p0 + 4*i);
      rn1[i] = *(const f32x4*)(p1 + 4*i);
      red[i] = *(const f32x4*)(pe + 4*i);
    }
    if (gw + NWAVES < tiles16) loadIdx(gw + NWAVES, e0n, e1n);
    writeX(rn0, 0); writeX(rn1, 1); writeX(red, 2);
  }

  // ---- barrier-free main loop: each wave self-paced ----
  for (long t = gw; t < tiles16; t += NWAVES) {
    const bool hn = (t + NWAVES) < tiles16;

    // 1. issue next tile's gathers early (hide HBM latency under compute)
    if (hn) {
      const float* p0 = node_state + (long)e0n*NFEAT + sc*16;
      const float* p1 = node_state + (long)e1n*NFEAT + sc*16;
      const float* pe = edge_state + ((t + NWAVES)*WTILE + er)*NFEAT + sc*16;
      #pragma unroll
      for (int i = 0; i < 4; ++i) {
        rn0[i] = *(const f32x4*)(p0 + 4*i);
        rn1[i] = *(const f32x4*)(p1 + 4*i);
        red[i] = *(const f32x4*)(pe + 4*i);
      }
    }
    // 2. indices two tiles ahead
    int e0p = 0, e1p = 0;
    if (t + 2*NWAVES < tiles16) loadIdx(t + 2*NWAVES, e0p, e1p);

    // 3a. GEMM1 (swapped): D'[hid][edge] = W1 . X^T, bias-init
    f32x4 acc1[8];
    #pragma unroll
    for (int hi = 0; hi < 8; ++hi) acc1[hi] = b1v[hi];
    #pragma unroll
    for (int ks = 0; ks < 6; ++ks) {
      const int p = ks >> 1;
      short8 bx = *(const short8*)(Xw + (p*WTILE + li)*XSTR + (ks & 1)*32 + 8*lg);
      #pragma unroll
      for (int hi = 0; hi < 8; ++hi) {
        short8 aw = *(const short8*)(W1l + (hi*16 + li)*W1STR + 32*ks + 8*lg);
        acc1[hi] = __builtin_amdgcn_mfma_f32_16x16x32_bf16(aw, bx, acc1[hi], 0, 0, 0);
      }
    }

    // 3b. shifted softplus + pack into GEMM2 A fragments (no LDS round-trip)
    short8 a2[4];
    #pragma unroll
    for (int q = 0; q < 4; ++q) {
      f32x4 lo = acc1[2*q], hi4 = acc1[2*q + 1];
      short8 v = { f2bf(sp_m_ln2(lo[0])),  f2bf(sp_m_ln2(lo[1])),
                   f2bf(sp_m_ln2(lo[2])),  f2bf(sp_m_ln2(lo[3])),
                   f2bf(sp_m_ln2(hi4[0])), f2bf(sp_m_ln2(hi4[1])),
                   f2bf(sp_m_ln2(hi4[2])), f2bf(sp_m_ln2(hi4[3])) };
      a2[q] = v;
    }

    // 3c. GEMM2: out[edge][feat] = H . W2^T, bias-init
    f32x4 acc2[4];
    #pragma unroll
    for (int ni = 0; ni < 4; ++ni) { f32x4 z = {b2v[ni], b2v[ni], b2v[ni], b2v[ni]}; acc2[ni] = z; }
    #pragma unroll
    for (int q = 0; q < 4; ++q)
      #pragma unroll
      for (int ni = 0; ni < 4; ++ni)
        acc2[ni] = __builtin_amdgcn_mfma_f32_16x16x32_bf16(a2[q], w2f[q][ni], acc2[ni], 0, 0, 0);

    // 3d. store
    { float* op = out + (t*WTILE + 4*lg)*OUTD + li;
      #pragma unroll
      for (int ni = 0; ni < 4; ++ni)
        #pragma unroll
        for (int r = 0; r < 4; ++r)
          op[(long)r*OUTD + ni*16] = acc2[ni][r];
    }

    // 4. write next tile into this wave's panels (same-wave DS ordering; no barrier)
    if (hn) { writeX(rn0, 0); writeX(rn1, 1); writeX(red, 2); }
    e0n = e0p; e1n = e1p;
  }
}

extern "C" void kernel_launch(void* const* d_in, const int* in_sizes, int n_in,
                              void* d_out, int out_size, void* d_ws, size_t ws_size,
                              hipStream_t stream) {
  const float* edge_state = (const float*)d_in[0];
  const int*   edges_i    = (const int*)d_in[1];
  const float* node_state = (const float*)d_in[2];
  const float* W1g        = (const float*)d_in[3];
  const float* b1g        = (const float*)d_in[4];
  const float* W2g        = (const float*)d_in[5];
  const float* b2g        = (const float*)d_in[6];
  float* out = (float*)d_out;
  int*   flag = (int*)d_ws;

  const int E = in_sizes[0] / NFEAT;      // 1,000,000
  const int tiles16 = E / WTILE;          // 62,500

  detect_mode<<<dim3(1), dim3(256), 0, stream>>>(edges_i, flag);

  (void)hipFuncSetAttribute((const void*)edge_mlp,
                            hipFuncAttributeMaxDynamicSharedMemorySize, SMEM_BYTES);
  edge_mlp<<<dim3(GRID), dim3(256), SMEM_BYTES, stream>>>(
      edge_state, edges_i, node_state, W1g, b1g, W2g, b2g, out, flag, tiles16);
}